// Round 1
// 933.129 us; speedup vs baseline: 1.0424x; 1.0424x over previous
//
#include <hip/hip_runtime.h>
#include <hip/hip_bf16.h>
#include <hip/hip_cooperative_groups.h>

namespace cg = cooperative_groups;

using bf16 = __hip_bfloat16;

typedef short s16x8 __attribute__((ext_vector_type(8)));
typedef float f32x4 __attribute__((ext_vector_type(4)));

#define TPB 512
#define MFMA16(a, b, c) __builtin_amdgcn_mfma_f32_16x16x32_bf16((a), (b), (c), 0, 0, 0)

__device__ __forceinline__ float b2f(bf16 h) { return __bfloat162float(h); }
__device__ __forceinline__ bf16  f2b(float f) { return __float2bfloat16(f); }
__device__ __forceinline__ void unpack2(unsigned int v, float& lo, float& hi) {
  lo = __builtin_bit_cast(float, v << 16);
  hi = __builtin_bit_cast(float, v & 0xffff0000u);
}
__device__ __forceinline__ void unpack8(uint4 u, float* f) {
  unpack2(u.x, f[0], f[1]); unpack2(u.y, f[2], f[3]);
  unpack2(u.z, f[4], f[5]); unpack2(u.w, f[6], f[7]);
}
__device__ __forceinline__ unsigned int pack2(float a, float b) {
  unsigned int lo = (unsigned int)__builtin_bit_cast(unsigned short, __float2bfloat16(a));
  unsigned int hi = (unsigned int)__builtin_bit_cast(unsigned short, __float2bfloat16(b));
  return lo | (hi << 16);
}
__device__ __forceinline__ s16x8 cvt8(float4 a, float4 b) {
  uint4 u;
  u.x = pack2(a.x, a.y); u.y = pack2(a.z, a.w);
  u.z = pack2(b.x, b.y); u.w = pack2(b.z, b.w);
  return __builtin_bit_cast(s16x8, u);
}

// LDS plan (bytes) — all internal tensors bf16, inputs converted at load:
//   patch  51200  current-source 10x10x256 halo patch (bf16)
//   R1     36864  union: dwT[r][c] (stride 264) -> vA[c][r] (stride 72) -> outT
//   R2     36864  V1 (img, alpha-scaled) in A-layout [c][r]
//   probs1  9216  P1 [p][r] bf16 (stride 72)   probs2 9216
//   q1/k1/q2/k2 4*2048   red 4096   stats 256     total = 155904 <= 163840
struct __align__(16) SMem {
  bf16 patch[256 * 100];
  union {
    bf16 dwT[64 * 264];
    bf16 vA[256 * 72];
    bf16 outT[256 * 72];
  } R1;
  bf16 R2[256 * 72];
  bf16 probs1[64 * 72];
  bf16 probs2[64 * 72];
  bf16 q1[16 * 64];
  bf16 k1[16 * 64];
  bf16 q2[16 * 64];
  bf16 k2[16 * 64];
  float red[2 * 8 * 64];
  float stats[64];
};

// ---- patch load (fp32 -> bf16): src[b][c][by*8-1 .. +10][bx*8-1 .. +10], zero halo ----
__device__ __forceinline__ void load_patch(SMem& sm, const float* __restrict__ src,
                                           int b, int by, int bx, int tid) {
  const int gx4 = bx * 8;
  for (int u = tid; u < 2560; u += TPB) {
    int c = u / 10, py = u - c * 10;
    int gy = by * 8 + py - 1;
    unsigned int* d32 = (unsigned int*)&sm.patch[c * 100 + py * 10];
    if (gy < 0 || gy > 127) {
      #pragma unroll
      for (int i = 0; i < 5; i++) d32[i] = 0u;
      continue;
    }
    const float* srow = src + (((long long)(b * 256 + c)) << 14) + ((long long)gy << 7);
    float4 t1 = *(const float4*)(srow + gx4);
    float4 t2 = *(const float4*)(srow + gx4 + 4);
    float first = (bx > 0) ? srow[gx4 - 1] : 0.0f;
    float last  = (bx < 15) ? srow[gx4 + 8] : 0.0f;
    d32[0] = pack2(first, t1.x);
    d32[1] = pack2(t1.y, t1.z);
    d32[2] = pack2(t1.w, t2.x);
    d32[3] = pack2(t2.y, t2.z);
    d32[4] = pack2(t2.w, last);
  }
}

__device__ __forceinline__ void load_prow(const bf16* p, float* r) {
  const unsigned int* q = (const unsigned int*)p;  // 4B-aligned: (c*100+py*10)*2
  #pragma unroll
  for (int i = 0; i < 5; i++) unpack2(q[i], r[2 * i], r[2 * i + 1]);
}

// ---- depthwise 3x3 (SAME) on resident patch -> R1.dwT[r][c] (+bias, fp32 weights) ----
__device__ __forceinline__ void dw_phase(SMem& sm, const float* __restrict__ w9,
                                         const float* __restrict__ bias, int tid) {
  int c = tid & 255, h = tid >> 8;  // h: pixel half (rows 4h..4h+3)
  float wr[9];
  #pragma unroll
  for (int i = 0; i < 9; i++) wr[i] = w9[c * 9 + i];
  float bs = bias[c];
  const bf16* prow = &sm.patch[c * 100];
  float r0[10], r1[10], r2[10];
  load_prow(prow + (4 * h) * 10, r0);
  load_prow(prow + (4 * h + 1) * 10, r1);
  bf16* dst = sm.R1.dwT;
  #pragma unroll
  for (int t = 0; t < 4; t++) {
    int ly = 4 * h + t;
    load_prow(prow + (ly + 2) * 10, r2);
    #pragma unroll
    for (int lx = 0; lx < 8; lx++) {
      float a = bs
        + r0[lx] * wr[0] + r0[lx + 1] * wr[1] + r0[lx + 2] * wr[2]
        + r1[lx] * wr[3] + r1[lx + 1] * wr[4] + r1[lx + 2] * wr[5]
        + r2[lx] * wr[6] + r2[lx + 1] * wr[7] + r2[lx + 2] * wr[8];
      dst[(ly * 8 + lx) * 264 + c] = f2b(a);
    }
    #pragma unroll
    for (int i = 0; i < 10; i++) { r0[i] = r1[i]; r1[i] = r2[i]; }
  }
}

// ---- pointwise 16x256 (q or k), scalar fp32 weights; dst[o][p] bf16 ----
__device__ __forceinline__ void pw_qk(SMem& sm, const float* __restrict__ w,
                                      const float* __restrict__ bias, bf16* dst,
                                      float scale, int tid) {
  int p = tid & 63;
  int og = __builtin_amdgcn_readfirstlane(tid >> 6);  // wave-uniform -> scalar weight base
  const bf16* dwp = &sm.R1.dwT[p * 264];
  float acc0 = 0.f, acc1 = 0.f;
  #pragma unroll 4
  for (int c0 = 0; c0 < 256; c0 += 8) {
    uint4 du = *(const uint4*)(dwp + c0);
    float d[8]; unpack8(du, d);
    const float* w0 = w + og * 256 + c0;
    const float* w1 = w + (og + 8) * 256 + c0;
    float4 w0a = *(const float4*)w0, w0b = *(const float4*)(w0 + 4);
    float4 w1a = *(const float4*)w1, w1b = *(const float4*)(w1 + 4);
    acc0 += w0a.x * d[0] + w0a.y * d[1] + w0a.z * d[2] + w0a.w * d[3]
          + w0b.x * d[4] + w0b.y * d[5] + w0b.z * d[6] + w0b.w * d[7];
    acc1 += w1a.x * d[0] + w1a.y * d[1] + w1a.z * d[2] + w1a.w * d[3]
          + w1b.x * d[4] + w1b.y * d[5] + w1b.z * d[6] + w1b.w * d[7];
  }
  dst[og * 64 + p]       = f2b(scale * (acc0 + bias[og]));
  dst[(og + 8) * 64 + p] = f2b(scale * (acc1 + bias[og + 8]));
}

// ---- scores + softmax over r; probs[p][r] bf16 (B^T layout for out-GEMM) ----
__device__ __forceinline__ void scores_softmax(SMem& sm, const bf16* q, const bf16* k,
                                               bf16* probs, int tid) {
  int p = tid & 63, rq = tid >> 6;
  int r0 = rq * 8;
  float s[8] = {0, 0, 0, 0, 0, 0, 0, 0};
  #pragma unroll 4
  for (int o = 0; o < 16; o++) {
    float qv = b2f(q[o * 64 + p]);
    uint4 ku = *(const uint4*)(k + o * 64 + r0);
    float kf[8]; unpack8(ku, kf);
    #pragma unroll
    for (int j = 0; j < 8; j++) s[j] += qv * kf[j];
  }
  float m = s[0];
  #pragma unroll
  for (int j = 1; j < 8; j++) m = fmaxf(m, s[j]);
  sm.red[rq * 64 + p] = m;
  __syncthreads();
  float M = sm.red[p];
  #pragma unroll
  for (int j = 1; j < 8; j++) M = fmaxf(M, sm.red[j * 64 + p]);
  float e[8], sum = 0.f;
  #pragma unroll
  for (int j = 0; j < 8; j++) { e[j] = __expf(s[j] - M); sum += e[j]; }
  sm.red[512 + rq * 64 + p] = sum;
  __syncthreads();
  float S = 0.f;
  #pragma unroll
  for (int j = 0; j < 8; j++) S += sm.red[512 + j * 64 + p];
  float inv = 1.0f / S;
  uint4 pk;
  pk.x = pack2(e[0] * inv, e[1] * inv);
  pk.y = pack2(e[2] * inv, e[3] * inv);
  pk.z = pack2(e[4] * inv, e[5] * inv);
  pk.w = pack2(e[6] * inv, e[7] * inv);
  *(uint4*)(probs + p * 72 + r0) = pk;
}

// ---- pointwise 256x256 via MFMA: V = scale*(vpw . dw + vb) -> dstVA[c][r] ----
__device__ __forceinline__ void vgemm(SMem& sm, const float* __restrict__ vpw,
                                      const float* __restrict__ vpb, bf16* dstVA,
                                      float scale, int tid) {
  int lane = tid & 63;
  int wv = __builtin_amdgcn_readfirstlane(tid >> 6);
  int quad = lane >> 4, l16 = lane & 15;
  int m0 = wv * 2;
  f32x4 acc[2][4];
  #pragma unroll
  for (int a = 0; a < 2; a++)
    #pragma unroll
    for (int n = 0; n < 4; n++) acc[a][n] = (f32x4){0.f, 0.f, 0.f, 0.f};
  const bf16* dwT = sm.R1.dwT;
  #pragma unroll 2
  for (int kt = 0; kt < 8; kt++) {
    int k0 = kt * 32 + quad * 8;
    const float* ar0 = vpw + (m0 * 16 + l16) * 256 + k0;
    const float* ar1 = vpw + ((m0 + 1) * 16 + l16) * 256 + k0;
    s16x8 a0 = cvt8(*(const float4*)ar0, *(const float4*)(ar0 + 4));
    s16x8 a1 = cvt8(*(const float4*)ar1, *(const float4*)(ar1 + 4));
    s16x8 bF[4];
    #pragma unroll
    for (int n = 0; n < 4; n++)
      bF[n] = __builtin_bit_cast(s16x8, *(const uint4*)(dwT + (n * 16 + l16) * 264 + k0));
    #pragma unroll
    for (int n = 0; n < 4; n++) {
      acc[0][n] = MFMA16(a0, bF[n], acc[0][n]);
      acc[1][n] = MFMA16(a1, bF[n], acc[1][n]);
    }
  }
  __syncthreads();  // dstVA may alias dwT (V2): all reads done before writes
  #pragma unroll
  for (int a = 0; a < 2; a++) {
    #pragma unroll
    for (int i = 0; i < 4; i++) {
      int c = (m0 + a) * 16 + quad * 4 + i;
      float bs = vpb[c];
      #pragma unroll
      for (int n = 0; n < 4; n++) {
        int r = n * 16 + l16;
        dstVA[c * 72 + r] = f2b(scale * (acc[a][n][i] + bs));
      }
    }
  }
}

// ---- out[c][p] += V[c][r] . P[p][r] via MFMA (K=64) ----
__device__ __forceinline__ void ogemm(const bf16* __restrict__ vA, const bf16* __restrict__ probs,
                                      f32x4 acc[2][4], int tid) {
  int lane = tid & 63;
  int wv = __builtin_amdgcn_readfirstlane(tid >> 6);
  int quad = lane >> 4, l16 = lane & 15;
  int m0 = wv * 2;
  #pragma unroll
  for (int kt = 0; kt < 2; kt++) {
    int k0 = kt * 32 + quad * 8;
    s16x8 a0 = __builtin_bit_cast(s16x8, *(const uint4*)(vA + (m0 * 16 + l16) * 72 + k0));
    s16x8 a1 = __builtin_bit_cast(s16x8, *(const uint4*)(vA + ((m0 + 1) * 16 + l16) * 72 + k0));
    #pragma unroll
    for (int n = 0; n < 4; n++) {
      s16x8 bF = __builtin_bit_cast(s16x8, *(const uint4*)(probs + (n * 16 + l16) * 72 + k0));
      acc[0][n] = MFMA16(a0, bF, acc[0][n]);
      acc[1][n] = MFMA16(a1, bF, acc[1][n]);
    }
  }
}

// ---- += resident-patch center (the 8x8 interior) at the C-frag positions ----
__device__ __forceinline__ void add_center(SMem& sm, f32x4 acc[2][4], int tid) {
  int lane = tid & 63, wv = tid >> 6, quad = lane >> 4, l16 = lane & 15;
  int m0 = wv * 2;
  #pragma unroll
  for (int a = 0; a < 2; a++)
    #pragma unroll
    for (int i = 0; i < 4; i++) {
      int c = (m0 + a) * 16 + quad * 4 + i;
      const bf16* prow = &sm.patch[c * 100];
      #pragma unroll
      for (int n = 0; n < 4; n++) {
        int p = n * 16 + l16;
        int ly = p >> 3, lx = p & 7;
        acc[a][n][i] += b2f(prow[(ly + 1) * 10 + (lx + 1)]);
      }
    }
}

// Persistent cooperative kernel: 256 blocks (1/CU), 8 tiles each.
// Per-tile fused bf16 output is stashed in per-thread scratch (runtime-indexed
// array -> private/scratch, 512 B/thread), grid.sync(), then GroupNorm is
// applied from the completed gstats and written directly -> gn_apply deleted.
__global__ __launch_bounds__(TPB, 2) void bicaf_fused(
    const float* __restrict__ img, const float* __restrict__ msk,
    const float* __restrict__ qdw_w, const float* __restrict__ qdw_b,
    const float* __restrict__ kdw_w, const float* __restrict__ kdw_b,
    const float* __restrict__ vdw_w, const float* __restrict__ vdw_b,
    const float* __restrict__ qpw_w, const float* __restrict__ qpw_b,
    const float* __restrict__ kpw_w, const float* __restrict__ kpw_b,
    const float* __restrict__ vpw_w, const float* __restrict__ vpw_b,
    const float* __restrict__ alphap, const float* __restrict__ betap,
    const float* __restrict__ gw, const float* __restrict__ gb,
    float* __restrict__ out, float* __restrict__ gstats) {
  __shared__ SMem sm;
  int tid = threadIdx.x;
  int j = blockIdx.x;
  float alpha = alphap[0], beta = betap[0];

  // per-tile fused output: 16 dwords (32 bf16) per thread per tile.
  // runtime-indexed -> scratch (intentional: carries data across grid.sync()).
  unsigned int stash[8][16];

  #pragma unroll 1
  for (int t = 0; t < 8; ++t) {
    // i = j + 256*t is bijective over [0,2048); preserves the original swizzle:
    // bx and i&7 (XCD slice) are invariant per block across t.
    int i = j + (t << 8);
    int bx = (i >> 3) & 15;
    int gi = (i & 7) | ((i >> 7) << 3);
    int b = gi >> 4, by = gi & 15;

    if (tid < 64) sm.stats[tid] = 0.f;

    // ================= stage A: img patch =================
    load_patch(sm, img, b, by, bx, tid);
    __syncthreads();
    dw_phase(sm, qdw_w, qdw_b, tid); __syncthreads();
    pw_qk(sm, qpw_w, qpw_b, sm.q2, 0.25f, tid); __syncthreads();   // Q2 (attn2 q=img), 1/sqrt(16) folded
    dw_phase(sm, kdw_w, kdw_b, tid); __syncthreads();
    pw_qk(sm, kpw_w, kpw_b, sm.k1, 1.0f, tid); __syncthreads();    // K1 (attn1 k=img)
    dw_phase(sm, vdw_w, vdw_b, tid); __syncthreads();
    vgemm(sm, vpw_w, vpw_b, sm.R2, alpha, tid);                    // V1 (attn1 v=img), alpha folded

    f32x4 facc[2][4];
    #pragma unroll
    for (int a = 0; a < 2; a++)
      #pragma unroll
      for (int n = 0; n < 4; n++) facc[a][n] = (f32x4){0.f, 0.f, 0.f, 0.f};
    add_center(sm, facc, tid);                                     // += img
    __syncthreads();

    // ================= stage B: mask patch =================
    load_patch(sm, msk, b, by, bx, tid);
    __syncthreads();
    dw_phase(sm, qdw_w, qdw_b, tid); __syncthreads();
    pw_qk(sm, qpw_w, qpw_b, sm.q1, 0.25f, tid); __syncthreads();   // Q1 (attn1 q=mask)
    dw_phase(sm, kdw_w, kdw_b, tid); __syncthreads();
    pw_qk(sm, kpw_w, kpw_b, sm.k2, 1.0f, tid); __syncthreads();    // K2 (attn2 k=mask)
    dw_phase(sm, vdw_w, vdw_b, tid); __syncthreads();
    vgemm(sm, vpw_w, vpw_b, sm.R1.vA, beta, tid);                  // V2 (attn2 v=mask), beta folded
    __syncthreads();
    scores_softmax(sm, sm.q1, sm.k1, sm.probs1, tid); __syncthreads();
    scores_softmax(sm, sm.q2, sm.k2, sm.probs2, tid); __syncthreads();
    ogemm(sm.R1.vA, sm.probs2, facc, tid);                         // += beta*img_enhanced
    ogemm(sm.R2, sm.probs1, facc, tid);                            // += alpha*mask_enhanced
    add_center(sm, facc, tid);                                     // += mask

    // GroupNorm partial stats (fp32, pre-rounding)
    {
      int lane = tid & 63, wv = tid >> 6, quad = lane >> 4;
      int m0 = wv * 2;
      #pragma unroll
      for (int a = 0; a < 2; a++) {
        int g = (((m0 + a) * 16 + quad * 4) >> 3);
        float s = 0.f, ss = 0.f;
        #pragma unroll
        for (int n = 0; n < 4; n++)
          #pragma unroll
          for (int ii = 0; ii < 4; ii++) { float v = facc[a][n][ii]; s += v; ss += v * v; }
        atomicAdd(&sm.stats[g * 2], s);
        atomicAdd(&sm.stats[g * 2 + 1], ss);
      }
    }
    __syncthreads();  // all ogemm/add_center LDS reads done; stats complete

    if (tid < 64) atomicAdd(&gstats[b * 64 + tid], sm.stats[tid]);

    // stash fused (bf16-rounded, identical rounding to previous outT path)
    #pragma unroll
    for (int a = 0; a < 2; a++)
      #pragma unroll
      for (int n = 0; n < 4; n++) {
        stash[t][a * 8 + n * 2 + 0] = pack2(facc[a][n][0], facc[a][n][1]);
        stash[t][a * 8 + n * 2 + 1] = pack2(facc[a][n][2], facc[a][n][3]);
      }
  }

  cg::this_grid().sync();  // all gstats atomics complete & visible

  {
    int c = tid & 255, h = tid >> 8;
    float gwc = gw[c], gbc = gb[c];
    int lane = tid & 63, wv = tid >> 6, quad = lane >> 4, l16 = lane & 15;
    int m0 = wv * 2;

    #pragma unroll 1
    for (int t = 0; t < 8; ++t) {
      int i = j + (t << 8);
      int bx = (i >> 3) & 15;
      int gi = (i & 7) | ((i >> 7) << 3);
      int b = gi >> 4, by = gi & 15;

      // unpack stash -> outT (raw bf16 bit moves, no re-rounding)
      {
        unsigned short* oT = (unsigned short*)sm.R1.outT;
        #pragma unroll
        for (int a = 0; a < 2; a++) {
          int cb = (m0 + a) * 16 + quad * 4;
          #pragma unroll
          for (int n = 0; n < 4; n++) {
            unsigned int d0 = stash[t][a * 8 + n * 2];
            unsigned int d1 = stash[t][a * 8 + n * 2 + 1];
            int col = n * 16 + l16;
            oT[(cb + 0) * 72 + col] = (unsigned short)(d0 & 0xffffu);
            oT[(cb + 1) * 72 + col] = (unsigned short)(d0 >> 16);
            oT[(cb + 2) * 72 + col] = (unsigned short)(d1 & 0xffffu);
            oT[(cb + 3) * 72 + col] = (unsigned short)(d1 >> 16);
          }
        }
      }
      __syncthreads();

      // GroupNorm apply + coalesced store (same math/rounding as old gn_apply)
      {
        int g = c >> 3;
        float sum = gstats[b * 64 + g * 2], ssum = gstats[b * 64 + g * 2 + 1];
        const float inv_n = 1.0f / 131072.0f;
        float mean = sum * inv_n;
        float var = ssum * inv_n - mean * mean;
        float rstd = rsqrtf(var + 1e-5f);
        float scl = gwc * rstd;
        float sh = gbc - mean * scl;
        float* obase = out + (((long long)(b * 256 + c)) << 14) + (long long)(by * 8) * 128 + bx * 8;
        #pragma unroll
        for (int r4 = 0; r4 < 4; r4++) {
          int ly = 4 * h + r4;
          uint4 v = *(const uint4*)&sm.R1.outT[c * 72 + ly * 8];
          float f[8]; unpack8(v, f);
          #pragma unroll
          for (int q = 0; q < 8; q++) f[q] = f[q] * scl + sh;
          *(float4*)(obase + ly * 128)     = make_float4(f[0], f[1], f[2], f[3]);
          *(float4*)(obase + ly * 128 + 4) = make_float4(f[4], f[5], f[6], f[7]);
        }
      }
      __syncthreads();  // outT reused next tile
    }
  }
}

extern "C" void kernel_launch(void* const* d_in, const int* in_sizes, int n_in,
                              void* d_out, int out_size, void* d_ws, size_t ws_size,
                              hipStream_t stream) {
  (void)in_sizes; (void)n_in; (void)out_size; (void)ws_size;
  const float* img    = (const float*)d_in[0];
  const float* msk    = (const float*)d_in[1];
  const float* qdw_w  = (const float*)d_in[2];
  const float* qdw_b  = (const float*)d_in[3];
  const float* kdw_w  = (const float*)d_in[4];
  const float* kdw_b  = (const float*)d_in[5];
  const float* vdw_w  = (const float*)d_in[6];
  const float* vdw_b  = (const float*)d_in[7];
  const float* qpw_w  = (const float*)d_in[8];
  const float* qpw_b  = (const float*)d_in[9];
  const float* kpw_w  = (const float*)d_in[10];
  const float* kpw_b  = (const float*)d_in[11];
  const float* vpw_w  = (const float*)d_in[12];
  const float* vpw_b  = (const float*)d_in[13];
  const float* alphap = (const float*)d_in[14];
  const float* betap  = (const float*)d_in[15];
  const float* gn_w   = (const float*)d_in[16];
  const float* gn_b   = (const float*)d_in[17];
  float* out = (float*)d_out;
  float* gstats = (float*)d_ws;  // 8*64 floats = 2048 B

  hipMemsetAsync(d_ws, 0, 2048, stream);
  void* args[] = {
    (void*)&img, (void*)&msk, (void*)&qdw_w, (void*)&qdw_b,
    (void*)&kdw_w, (void*)&kdw_b, (void*)&vdw_w, (void*)&vdw_b,
    (void*)&qpw_w, (void*)&qpw_b, (void*)&kpw_w, (void*)&kpw_b,
    (void*)&vpw_w, (void*)&vpw_b, (void*)&alphap, (void*)&betap,
    (void*)&gn_w, (void*)&gn_b, (void*)&out, (void*)&gstats
  };
  hipLaunchCooperativeKernel(reinterpret_cast<void*>(bicaf_fused),
                             dim3(256), dim3(TPB), args, 0, stream);
}

// Round 3
// 872.156 us; speedup vs baseline: 1.1153x; 1.0699x over previous
//
#include <hip/hip_runtime.h>
#include <hip/hip_bf16.h>

using bf16 = __hip_bfloat16;

typedef short s16x8 __attribute__((ext_vector_type(8)));
typedef float f32x4 __attribute__((ext_vector_type(4)));

#define TPB 512
#define MFMA16(a, b, c) __builtin_amdgcn_mfma_f32_16x16x32_bf16((a), (b), (c), 0, 0, 0)

__device__ __forceinline__ float b2f(bf16 h) { return __bfloat162float(h); }
__device__ __forceinline__ bf16  f2b(float f) { return __float2bfloat16(f); }
__device__ __forceinline__ void unpack2(unsigned int v, float& lo, float& hi) {
  lo = __builtin_bit_cast(float, v << 16);
  hi = __builtin_bit_cast(float, v & 0xffff0000u);
}
__device__ __forceinline__ void unpack8(uint4 u, float* f) {
  unpack2(u.x, f[0], f[1]); unpack2(u.y, f[2], f[3]);
  unpack2(u.z, f[4], f[5]); unpack2(u.w, f[6], f[7]);
}
__device__ __forceinline__ unsigned int pack2(float a, float b) {
  unsigned int lo = (unsigned int)__builtin_bit_cast(unsigned short, __float2bfloat16(a));
  unsigned int hi = (unsigned int)__builtin_bit_cast(unsigned short, __float2bfloat16(b));
  return lo | (hi << 16);
}
__device__ __forceinline__ s16x8 cvt8(float4 a, float4 b) {
  uint4 u;
  u.x = pack2(a.x, a.y); u.y = pack2(a.z, a.w);
  u.z = pack2(b.x, b.y); u.w = pack2(b.z, b.w);
  return __builtin_bit_cast(s16x8, u);
}

// LDS plan (bytes), sized for 2 blocks/CU (<= 81920):
//   U0    25600  union: patchH (128ch x 10x10 halo, bf16) | probs1+probs2 (written
//                after last patch read of the tile; read by ogemm)
//   R1    36864  union: dwT[r][c] stride 264 | vA[c][r] stride 72 | outT
//                per half-stage: dw(q/k/v, half0) writes cols 0..127, half1 phases
//                write cols 128..255 -> after dw_v(h1) full v-activation resident.
//   q1/k1/q2/k2 4*2048   red 4096   stats 256
//   total = 75008  -> 2 blocks/CU = 16 waves/CU (vs 8 before); NO cooperative
//   launch needed — plain launch, scheduler packs 2/CU if resources allow.
struct __align__(16) SMem {
  union {
    bf16 patchH[128 * 100];
    struct { bf16 probs1[64 * 72]; bf16 probs2[64 * 72]; } P;
  } U0;
  union {
    bf16 dwT[64 * 264];
    bf16 vA[256 * 72];
    bf16 outT[256 * 72];
  } R1;
  bf16 q1[16 * 64];
  bf16 k1[16 * 64];
  bf16 q2[16 * 64];
  bf16 k2[16 * 64];
  float red[2 * 8 * 64];
  float stats[64];
};

// ---- half-patch load (fp32 -> bf16): channels [half*128, half*128+128) ----
__device__ __forceinline__ void load_patch_h(SMem& sm, const float* __restrict__ src,
                                             int b, int by, int bx, int half, int tid) {
  const int gx4 = bx * 8;
  for (int u = tid; u < 1280; u += TPB) {
    int cl = u / 10, py = u - cl * 10;
    int gy = by * 8 + py - 1;
    unsigned int* d32 = (unsigned int*)&sm.U0.patchH[cl * 100 + py * 10];
    if (gy < 0 || gy > 127) {
      #pragma unroll
      for (int i = 0; i < 5; i++) d32[i] = 0u;
      continue;
    }
    int cg = half * 128 + cl;
    const float* srow = src + (((long long)(b * 256 + cg)) << 14) + ((long long)gy << 7);
    float4 t1 = *(const float4*)(srow + gx4);
    float4 t2 = *(const float4*)(srow + gx4 + 4);
    float first = (bx > 0) ? srow[gx4 - 1] : 0.0f;
    float last  = (bx < 15) ? srow[gx4 + 8] : 0.0f;
    d32[0] = pack2(first, t1.x);
    d32[1] = pack2(t1.y, t1.z);
    d32[2] = pack2(t1.w, t2.x);
    d32[3] = pack2(t2.y, t2.z);
    d32[4] = pack2(t2.w, last);
  }
}

__device__ __forceinline__ void load_prow(const bf16* p, float* r) {
  const unsigned int* q = (const unsigned int*)p;  // 4B-aligned
  #pragma unroll
  for (int i = 0; i < 5; i++) unpack2(q[i], r[2 * i], r[2 * i + 1]);
}

// ---- depthwise 3x3 on resident half-patch -> dwT cols [half*128, +128) ----
// 512 threads / 128 channels: 4 threads per channel, 2 output rows each.
__device__ __forceinline__ void dw_phase_h(SMem& sm, const float* __restrict__ w9,
                                           const float* __restrict__ bias, int half, int tid) {
  int cl = tid & 127, h = tid >> 7;  // h in 0..3 -> rows 2h, 2h+1
  int c = half * 128 + cl;
  float wr[9];
  #pragma unroll
  for (int i = 0; i < 9; i++) wr[i] = w9[c * 9 + i];
  float bs = bias[c];
  const bf16* prow = &sm.U0.patchH[cl * 100];
  float r0[10], r1[10], r2[10];
  load_prow(prow + (2 * h) * 10, r0);
  load_prow(prow + (2 * h + 1) * 10, r1);
  bf16* dst = sm.R1.dwT;
  #pragma unroll
  for (int t = 0; t < 2; t++) {
    int ly = 2 * h + t;
    load_prow(prow + (ly + 2) * 10, r2);
    #pragma unroll
    for (int lx = 0; lx < 8; lx++) {
      float a = bs
        + r0[lx] * wr[0] + r0[lx + 1] * wr[1] + r0[lx + 2] * wr[2]
        + r1[lx] * wr[3] + r1[lx + 1] * wr[4] + r1[lx + 2] * wr[5]
        + r2[lx] * wr[6] + r2[lx + 1] * wr[7] + r2[lx + 2] * wr[8];
      dst[(ly * 8 + lx) * 264 + c] = f2b(a);
    }
    #pragma unroll
    for (int i = 0; i < 10; i++) { r0[i] = r1[i]; r1[i] = r2[i]; }
  }
}

// ---- pointwise 16x256 (q or k): partial accumulate over channels [cb, cb+128) ----
__device__ __forceinline__ void pw_qk_part(SMem& sm, const float* __restrict__ w,
                                           int cb, float& acc0, float& acc1, int tid) {
  int p = tid & 63;
  int og = __builtin_amdgcn_readfirstlane(tid >> 6);
  const bf16* dwp = &sm.R1.dwT[p * 264];
  #pragma unroll 4
  for (int c0 = cb; c0 < cb + 128; c0 += 8) {
    uint4 du = *(const uint4*)(dwp + c0);
    float d[8]; unpack8(du, d);
    const float* w0 = w + og * 256 + c0;
    const float* w1 = w + (og + 8) * 256 + c0;
    float4 w0a = *(const float4*)w0, w0b = *(const float4*)(w0 + 4);
    float4 w1a = *(const float4*)w1, w1b = *(const float4*)(w1 + 4);
    acc0 += w0a.x * d[0] + w0a.y * d[1] + w0a.z * d[2] + w0a.w * d[3]
          + w0b.x * d[4] + w0b.y * d[5] + w0b.z * d[6] + w0b.w * d[7];
    acc1 += w1a.x * d[0] + w1a.y * d[1] + w1a.z * d[2] + w1a.w * d[3]
          + w1b.x * d[4] + w1b.y * d[5] + w1b.z * d[6] + w1b.w * d[7];
  }
}
__device__ __forceinline__ void pw_qk_fin(const float* __restrict__ bias, bf16* dst,
                                          float scale, float acc0, float acc1, int tid) {
  int p = tid & 63;
  int og = __builtin_amdgcn_readfirstlane(tid >> 6);
  dst[og * 64 + p]       = f2b(scale * (acc0 + bias[og]));
  dst[(og + 8) * 64 + p] = f2b(scale * (acc1 + bias[og + 8]));
}

// ---- scores + softmax over r; probs[p][r] bf16 (B^T layout for out-GEMM) ----
__device__ __forceinline__ void scores_softmax(SMem& sm, const bf16* q, const bf16* k,
                                               bf16* probs, int tid) {
  int p = tid & 63, rq = tid >> 6;
  int r0 = rq * 8;
  float s[8] = {0, 0, 0, 0, 0, 0, 0, 0};
  #pragma unroll 4
  for (int o = 0; o < 16; o++) {
    float qv = b2f(q[o * 64 + p]);
    uint4 ku = *(const uint4*)(k + o * 64 + r0);
    float kf[8]; unpack8(ku, kf);
    #pragma unroll
    for (int j = 0; j < 8; j++) s[j] += qv * kf[j];
  }
  float m = s[0];
  #pragma unroll
  for (int j = 1; j < 8; j++) m = fmaxf(m, s[j]);
  sm.red[rq * 64 + p] = m;
  __syncthreads();
  float M = sm.red[p];
  #pragma unroll
  for (int j = 1; j < 8; j++) M = fmaxf(M, sm.red[j * 64 + p]);
  float e[8], sum = 0.f;
  #pragma unroll
  for (int j = 0; j < 8; j++) { e[j] = __expf(s[j] - M); sum += e[j]; }
  sm.red[512 + rq * 64 + p] = sum;
  __syncthreads();
  float S = 0.f;
  #pragma unroll
  for (int j = 0; j < 8; j++) S += sm.red[512 + j * 64 + p];
  float inv = 1.0f / S;
  uint4 pk;
  pk.x = pack2(e[0] * inv, e[1] * inv);
  pk.y = pack2(e[2] * inv, e[3] * inv);
  pk.z = pack2(e[4] * inv, e[5] * inv);
  pk.w = pack2(e[6] * inv, e[7] * inv);
  *(uint4*)(probs + p * 72 + r0) = pk;
}

// ---- pointwise 256x256 via MFMA (full K, dwT holds v for all 256 ch) ----
__device__ __forceinline__ void vgemm(SMem& sm, const float* __restrict__ vpw,
                                      const float* __restrict__ vpb, bf16* dstVA,
                                      float scale, int tid) {
  int lane = tid & 63;
  int wv = __builtin_amdgcn_readfirstlane(tid >> 6);
  int quad = lane >> 4, l16 = lane & 15;
  int m0 = wv * 2;
  f32x4 acc[2][4];
  #pragma unroll
  for (int a = 0; a < 2; a++)
    #pragma unroll
    for (int n = 0; n < 4; n++) acc[a][n] = (f32x4){0.f, 0.f, 0.f, 0.f};
  const bf16* dwT = sm.R1.dwT;
  #pragma unroll 2
  for (int kt = 0; kt < 8; kt++) {
    int k0 = kt * 32 + quad * 8;
    const float* ar0 = vpw + (m0 * 16 + l16) * 256 + k0;
    const float* ar1 = vpw + ((m0 + 1) * 16 + l16) * 256 + k0;
    s16x8 a0 = cvt8(*(const float4*)ar0, *(const float4*)(ar0 + 4));
    s16x8 a1 = cvt8(*(const float4*)ar1, *(const float4*)(ar1 + 4));
    s16x8 bF[4];
    #pragma unroll
    for (int n = 0; n < 4; n++)
      bF[n] = __builtin_bit_cast(s16x8, *(const uint4*)(dwT + (n * 16 + l16) * 264 + k0));
    #pragma unroll
    for (int n = 0; n < 4; n++) {
      acc[0][n] = MFMA16(a0, bF[n], acc[0][n]);
      acc[1][n] = MFMA16(a1, bF[n], acc[1][n]);
    }
  }
  __syncthreads();  // dstVA aliases dwT: all reads done before writes
  #pragma unroll
  for (int a = 0; a < 2; a++) {
    #pragma unroll
    for (int i = 0; i < 4; i++) {
      int c = (m0 + a) * 16 + quad * 4 + i;
      float bs = vpb[c];
      #pragma unroll
      for (int n = 0; n < 4; n++) {
        int r = n * 16 + l16;
        dstVA[c * 72 + r] = f2b(scale * (acc[a][n][i] + bs));
      }
    }
  }
}

// ---- read back this thread's ogemm A-fragments of vA (16 VGPRs) ----
__device__ __forceinline__ void load_vfrags(const bf16* __restrict__ vA, uint4 vf[2][2], int tid) {
  int lane = tid & 63;
  int wv = __builtin_amdgcn_readfirstlane(tid >> 6);
  int quad = lane >> 4, l16 = lane & 15;
  int m0 = wv * 2;
  #pragma unroll
  for (int kt = 0; kt < 2; kt++) {
    int k0 = kt * 32 + quad * 8;
    vf[kt][0] = *(const uint4*)(vA + (m0 * 16 + l16) * 72 + k0);
    vf[kt][1] = *(const uint4*)(vA + ((m0 + 1) * 16 + l16) * 72 + k0);
  }
}

// ---- out[c][p] += V[c][r] . P[p][r] via MFMA (K=64), V from registers ----
__device__ __forceinline__ void ogemm_reg(const uint4 vf[2][2], const bf16* __restrict__ probs,
                                          f32x4 acc[2][4], int tid) {
  int lane = tid & 63, quad = lane >> 4, l16 = lane & 15;
  #pragma unroll
  for (int kt = 0; kt < 2; kt++) {
    int k0 = kt * 32 + quad * 8;
    s16x8 a0 = __builtin_bit_cast(s16x8, vf[kt][0]);
    s16x8 a1 = __builtin_bit_cast(s16x8, vf[kt][1]);
    #pragma unroll
    for (int n = 0; n < 4; n++) {
      s16x8 bF = __builtin_bit_cast(s16x8, *(const uint4*)(probs + (n * 16 + l16) * 72 + k0));
      acc[0][n] = MFMA16(a0, bF, acc[0][n]);
      acc[1][n] = MFMA16(a1, bF, acc[1][n]);
    }
  }
}

// ---- out[c][p] += V[c][r] . P[p][r] via MFMA (K=64), V from LDS ----
__device__ __forceinline__ void ogemm_lds(const bf16* __restrict__ vA, const bf16* __restrict__ probs,
                                          f32x4 acc[2][4], int tid) {
  int lane = tid & 63;
  int wv = __builtin_amdgcn_readfirstlane(tid >> 6);
  int quad = lane >> 4, l16 = lane & 15;
  int m0 = wv * 2;
  #pragma unroll
  for (int kt = 0; kt < 2; kt++) {
    int k0 = kt * 32 + quad * 8;
    s16x8 a0 = __builtin_bit_cast(s16x8, *(const uint4*)(vA + (m0 * 16 + l16) * 72 + k0));
    s16x8 a1 = __builtin_bit_cast(s16x8, *(const uint4*)(vA + ((m0 + 1) * 16 + l16) * 72 + k0));
    #pragma unroll
    for (int n = 0; n < 4; n++) {
      s16x8 bF = __builtin_bit_cast(s16x8, *(const uint4*)(probs + (n * 16 + l16) * 72 + k0));
      acc[0][n] = MFMA16(a0, bF, acc[0][n]);
      acc[1][n] = MFMA16(a1, bF, acc[1][n]);
    }
  }
}

// ---- += resident half-patch center at the C-frag positions ----
__device__ __forceinline__ void add_center_h(SMem& sm, f32x4 acc[2][4], int half, int tid) {
  int lane = tid & 63, wv = tid >> 6, quad = lane >> 4, l16 = lane & 15;
  int m0 = wv * 2;
  #pragma unroll
  for (int a = 0; a < 2; a++) {
    int cb = (m0 + a) * 16 + quad * 4;
    if ((cb >> 7) != half) continue;  // all 4 i's share the half
    #pragma unroll
    for (int i = 0; i < 4; i++) {
      const bf16* prow = &sm.U0.patchH[((cb + i) & 127) * 100];
      #pragma unroll
      for (int n = 0; n < 4; n++) {
        int p = n * 16 + l16;
        int ly = p >> 3, lx = p & 7;
        acc[a][n][i] += b2f(prow[(ly + 1) * 10 + (lx + 1)]);
      }
    }
  }
}

// Plain (non-cooperative) launch: 512 blocks, 4 tiles each. With 75 KB LDS and
// <=128 VGPRs the scheduler packs 2 blocks/CU (16 waves) — no co-residency
// requirement for correctness.
__global__ __launch_bounds__(TPB, 4) void bicaf_main(
    const float* __restrict__ img, const float* __restrict__ msk,
    const float* __restrict__ qdw_w, const float* __restrict__ qdw_b,
    const float* __restrict__ kdw_w, const float* __restrict__ kdw_b,
    const float* __restrict__ vdw_w, const float* __restrict__ vdw_b,
    const float* __restrict__ qpw_w, const float* __restrict__ qpw_b,
    const float* __restrict__ kpw_w, const float* __restrict__ kpw_b,
    const float* __restrict__ vpw_w, const float* __restrict__ vpw_b,
    const float* __restrict__ alphap, const float* __restrict__ betap,
    float* __restrict__ out, float* __restrict__ gstats) {
  __shared__ SMem sm;
  int tid = threadIdx.x;
  int j = blockIdx.x;
  float alpha = alphap[0], beta = betap[0];

  #pragma unroll 1
  for (int t = 0; t < 4; ++t) {
    // i = j + 512*t bijective over [0,2048); bx and i&7 (XCD slice) invariant per block.
    int i = j + (t << 9);
    int bx = (i >> 3) & 15;
    int gi = (i & 7) | ((i >> 7) << 3);
    int b = gi >> 4, by = gi & 15;

    if (tid < 64) sm.stats[tid] = 0.f;

    f32x4 facc[2][4];
    #pragma unroll
    for (int a = 0; a < 2; a++)
      #pragma unroll
      for (int n = 0; n < 4; n++) facc[a][n] = (f32x4){0.f, 0.f, 0.f, 0.f};

    float qa0, qa1, ka0, ka1;
    uint4 vf1[2][2];

    // ================= stage A: img =================
    load_patch_h(sm, img, b, by, bx, 0, tid); __syncthreads();
    dw_phase_h(sm, qdw_w, qdw_b, 0, tid); add_center_h(sm, facc, 0, tid); __syncthreads();
    qa0 = 0.f; qa1 = 0.f;
    pw_qk_part(sm, qpw_w, 0, qa0, qa1, tid); __syncthreads();
    dw_phase_h(sm, kdw_w, kdw_b, 0, tid); __syncthreads();
    ka0 = 0.f; ka1 = 0.f;
    pw_qk_part(sm, kpw_w, 0, ka0, ka1, tid); __syncthreads();
    dw_phase_h(sm, vdw_w, vdw_b, 0, tid); __syncthreads();
    load_patch_h(sm, img, b, by, bx, 1, tid); __syncthreads();
    dw_phase_h(sm, qdw_w, qdw_b, 1, tid); __syncthreads();
    pw_qk_part(sm, qpw_w, 128, qa0, qa1, tid);
    pw_qk_fin(qpw_b, sm.q2, 0.25f, qa0, qa1, tid); __syncthreads();   // Q2 (attn2 q=img)
    dw_phase_h(sm, kdw_w, kdw_b, 1, tid); __syncthreads();
    pw_qk_part(sm, kpw_w, 128, ka0, ka1, tid);
    pw_qk_fin(kpw_b, sm.k1, 1.0f, ka0, ka1, tid); __syncthreads();    // K1 (attn1 k=img)
    dw_phase_h(sm, vdw_w, vdw_b, 1, tid); add_center_h(sm, facc, 1, tid); __syncthreads();
    vgemm(sm, vpw_w, vpw_b, sm.R1.vA, alpha, tid);                    // V1 (alpha folded)
    __syncthreads();
    load_vfrags(sm.R1.vA, vf1, tid);                                  // V1 -> 16 VGPRs
    __syncthreads();

    // ================= stage B: mask =================
    load_patch_h(sm, msk, b, by, bx, 0, tid); __syncthreads();
    dw_phase_h(sm, qdw_w, qdw_b, 0, tid); add_center_h(sm, facc, 0, tid); __syncthreads();
    qa0 = 0.f; qa1 = 0.f;
    pw_qk_part(sm, qpw_w, 0, qa0, qa1, tid); __syncthreads();
    dw_phase_h(sm, kdw_w, kdw_b, 0, tid); __syncthreads();
    ka0 = 0.f; ka1 = 0.f;
    pw_qk_part(sm, kpw_w, 0, ka0, ka1, tid); __syncthreads();
    dw_phase_h(sm, vdw_w, vdw_b, 0, tid); __syncthreads();
    load_patch_h(sm, msk, b, by, bx, 1, tid); __syncthreads();
    dw_phase_h(sm, qdw_w, qdw_b, 1, tid); __syncthreads();
    pw_qk_part(sm, qpw_w, 128, qa0, qa1, tid);
    pw_qk_fin(qpw_b, sm.q1, 0.25f, qa0, qa1, tid); __syncthreads();   // Q1 (attn1 q=mask)
    dw_phase_h(sm, kdw_w, kdw_b, 1, tid); __syncthreads();
    pw_qk_part(sm, kpw_w, 128, ka0, ka1, tid);
    pw_qk_fin(kpw_b, sm.k2, 1.0f, ka0, ka1, tid); __syncthreads();    // K2 (attn2 k=mask)
    dw_phase_h(sm, vdw_w, vdw_b, 1, tid); add_center_h(sm, facc, 1, tid); __syncthreads();
    vgemm(sm, vpw_w, vpw_b, sm.R1.vA, beta, tid);                     // V2 (beta folded), stays in LDS
    __syncthreads();

    // softmax (patchH dead -> probs live in U0)
    scores_softmax(sm, sm.q1, sm.k1, sm.U0.P.probs1, tid); __syncthreads();
    scores_softmax(sm, sm.q2, sm.k2, sm.U0.P.probs2, tid); __syncthreads();
    ogemm_reg(vf1, sm.U0.P.probs1, facc, tid);                        // += alpha*mask_enhanced
    ogemm_lds(sm.R1.vA, sm.U0.P.probs2, facc, tid);                   // += beta*img_enhanced

    // GroupNorm partial stats (fp32, pre-rounding)
    {
      int lane = tid & 63, wv = tid >> 6, quad = lane >> 4;
      int m0 = wv * 2;
      #pragma unroll
      for (int a = 0; a < 2; a++) {
        int g = (((m0 + a) * 16 + quad * 4) >> 3);
        float s = 0.f, ss = 0.f;
        #pragma unroll
        for (int n = 0; n < 4; n++)
          #pragma unroll
          for (int ii = 0; ii < 4; ii++) { float v = facc[a][n][ii]; s += v; ss += v * v; }
        atomicAdd(&sm.stats[g * 2], s);
        atomicAdd(&sm.stats[g * 2 + 1], ss);
      }
    }
    __syncthreads();  // stats complete; vA/probs reads done before outT overwrite

    if (tid < 64) atomicAdd(&gstats[b * 64 + tid], sm.stats[tid]);

    // stash fused (bf16) into R1.outT for coalesced fp32 store
    {
      int lane = tid & 63, wv = tid >> 6, quad = lane >> 4, l16 = lane & 15;
      int m0 = wv * 2;
      #pragma unroll
      for (int a = 0; a < 2; a++)
        #pragma unroll
        for (int ii = 0; ii < 4; ii++) {
          int c = (m0 + a) * 16 + quad * 4 + ii;
          #pragma unroll
          for (int n = 0; n < 4; n++)
            sm.R1.outT[c * 72 + n * 16 + l16] = f2b(facc[a][n][ii]);
        }
    }
    __syncthreads();

    {
      int c = tid & 255, h = tid >> 8;
      float* obase = out + (((long long)(b * 256 + c)) << 14) + (long long)(by * 8) * 128 + bx * 8;
      #pragma unroll
      for (int t4 = 0; t4 < 4; t4++) {
        int ly = 4 * h + t4;
        uint4 v = *(const uint4*)&sm.R1.outT[c * 72 + ly * 8];
        float f[8]; unpack8(v, f);
        *(float4*)(obase + ly * 128)     = make_float4(f[0], f[1], f[2], f[3]);
        *(float4*)(obase + ly * 128 + 4) = make_float4(f[4], f[5], f[6], f[7]);
      }
    }
    __syncthreads();  // outT reads done before next tile reuses R1/U0
  }
}

__global__ __launch_bounds__(256) void gn_apply(float* __restrict__ out,
    const float* __restrict__ gstats, const float* __restrict__ gw,
    const float* __restrict__ gb) {
  long long idx = ((long long)blockIdx.x * 256 + threadIdx.x) * 8;
  int c = (int)((idx >> 14) & 255);
  int b = (int)(idx >> 22);
  int g = c >> 3;
  float sum = gstats[b * 64 + g * 2], ss = gstats[b * 64 + g * 2 + 1];
  const float inv_n = 1.0f / 131072.0f;
  float mean = sum * inv_n;
  float var = ss * inv_n - mean * mean;
  float rstd = rsqrtf(var + 1e-5f);
  float sc = gw[c] * rstd;
  float sh = gb[c] - mean * sc;
  float4 v0 = *(const float4*)(out + idx);
  float4 v1 = *(const float4*)(out + idx + 4);
  v0.x = v0.x * sc + sh; v0.y = v0.y * sc + sh;
  v0.z = v0.z * sc + sh; v0.w = v0.w * sc + sh;
  v1.x = v1.x * sc + sh; v1.y = v1.y * sc + sh;
  v1.z = v1.z * sc + sh; v1.w = v1.w * sc + sh;
  *(float4*)(out + idx) = v0;
  *(float4*)(out + idx + 4) = v1;
}

extern "C" void kernel_launch(void* const* d_in, const int* in_sizes, int n_in,
                              void* d_out, int out_size, void* d_ws, size_t ws_size,
                              hipStream_t stream) {
  (void)in_sizes; (void)n_in; (void)out_size; (void)ws_size;
  const float* img    = (const float*)d_in[0];
  const float* msk    = (const float*)d_in[1];
  const float* qdw_w  = (const float*)d_in[2];
  const float* qdw_b  = (const float*)d_in[3];
  const float* kdw_w  = (const float*)d_in[4];
  const float* kdw_b  = (const float*)d_in[5];
  const float* vdw_w  = (const float*)d_in[6];
  const float* vdw_b  = (const float*)d_in[7];
  const float* qpw_w  = (const float*)d_in[8];
  const float* qpw_b  = (const float*)d_in[9];
  const float* kpw_w  = (const float*)d_in[10];
  const float* kpw_b  = (const float*)d_in[11];
  const float* vpw_w  = (const float*)d_in[12];
  const float* vpw_b  = (const float*)d_in[13];
  const float* alphap = (const float*)d_in[14];
  const float* betap  = (const float*)d_in[15];
  const float* gn_w   = (const float*)d_in[16];
  const float* gn_b   = (const float*)d_in[17];
  float* out = (float*)d_out;
  float* gstats = (float*)d_ws;  // 8*64 floats = 2048 B

  hipMemsetAsync(d_ws, 0, 2048, stream);
  bicaf_main<<<dim3(512), dim3(TPB), 0, stream>>>(
      img, msk, qdw_w, qdw_b, kdw_w, kdw_b, vdw_w, vdw_b,
      qpw_w, qpw_b, kpw_w, kpw_b, vpw_w, vpw_b, alphap, betap, out, gstats);
  gn_apply<<<dim3(16384), dim3(256), 0, stream>>>(out, gstats, gn_w, gn_b);
}